// Round 1
// baseline (121.652 us; speedup 1.0000x reference)
//
#include <hip/hip_runtime.h>

#define T_LEN 256
#define N_LAYERS 128

__device__ __forceinline__ float fast_sig(float x) {
    // 1/(1+exp(-x)) via v_exp_f32 + v_rcp_f32
    float e = __builtin_amdgcn_exp2f(x * -1.442695040888963f);
    return __builtin_amdgcn_rcpf(1.0f + e);
}

__device__ __forceinline__ float fast_tanh(float x) {
    // tanh(x) = 2*sigmoid(2x) - 1
    float e = __builtin_amdgcn_exp2f(x * -2.885390081777926f);
    float s = __builtin_amdgcn_rcpf(1.0f + e);
    return fmaf(2.0f, s, -1.0f);
}

// One wave, 64 lanes, 2 GRU layers per lane (layers 2*lane and 2*lane+1).
// Anti-diagonal wavefront over (layer, time); lane-to-lane handoff via shfl_up.
__global__ __launch_bounds__(64, 1) void gru_stack_wavefront(
    const float* __restrict__ x,
    const float* __restrict__ w_ih,
    const float* __restrict__ w_hh,
    const float* __restrict__ b_ih,
    const float* __restrict__ b_hh,
    float* __restrict__ out)
{
    __shared__ float sx[T_LEN];
    const int lane = threadIdx.x;  // 0..63

    // stage x into LDS (coalesced, 4 per lane)
    #pragma unroll
    for (int i = 0; i < T_LEN / 64; ++i)
        sx[lane + 64 * i] = x[lane + 64 * i];

    const int la = 2 * lane;      // layer A
    const int lb = 2 * lane + 1;  // layer B

    // Per-layer params, gate order [r, z, n]; H=1 so each weight is a scalar.
    const float wiAr = w_ih[3 * la + 0], wiAz = w_ih[3 * la + 1], wiAn = w_ih[3 * la + 2];
    const float whAr = w_hh[3 * la + 0], whAz = w_hh[3 * la + 1], whAn = w_hh[3 * la + 2];
    const float biAr = b_ih[3 * la + 0], biAz = b_ih[3 * la + 1], biAn = b_ih[3 * la + 2];
    const float bhAr = b_hh[3 * la + 0], bhAz = b_hh[3 * la + 1], bhAn = b_hh[3 * la + 2];

    const float wiBr = w_ih[3 * lb + 0], wiBz = w_ih[3 * lb + 1], wiBn = w_ih[3 * lb + 2];
    const float whBr = w_hh[3 * lb + 0], whBz = w_hh[3 * lb + 1], whBn = w_hh[3 * lb + 2];
    const float biBr = b_ih[3 * lb + 0], biBz = b_ih[3 * lb + 1], biBn = b_ih[3 * lb + 2];
    const float bhBr = b_hh[3 * lb + 0], bhBz = b_hh[3 * lb + 1], bhBn = b_hh[3 * lb + 2];

    // Folded bias sums for r,z gates
    const float bAr = biAr + bhAr, bAz = biAz + bhAz;
    const float bBr = biBr + bhBr, bBz = biBz + bhBz;

    float hA = 0.0f, hB = 0.0f;
    // h-dependent gate pre-activations, precomputed off the input critical path.
    // cXr = wh_r*h + (bi_r+bh_r); cXz likewise; gXn = wh_n*h + bh_n. (h=0 now.)
    float cAr = bAr, cAz = bAz, gAn = bhAn;
    float cBr = bBr, cBz = bBz, gBn = bhBn;

    float out_val = 0.0f;
    __syncthreads();  // make sx visible (single wave: ~free)

    for (int s = 0; s < T_LEN + 63; ++s) {
        // lane i receives lane i-1's layer-(2i-1) output computed last step
        float up = __shfl_up(out_val, 1);
        float xin = sx[s & (T_LEN - 1)];  // only valid/used while s < T_LEN
        float in = (lane == 0) ? xin : up;
        int t = s - lane;
        if ((unsigned)t < (unsigned)T_LEN) {
            // ---- cell A (layer 2*lane), input = in ----
            float r = fast_sig(fmaf(wiAr, in, cAr));
            float z = fast_sig(fmaf(wiAz, in, cAz));
            float n = fast_tanh(fmaf(r, gAn, fmaf(wiAn, in, biAn)));
            hA = fmaf(z, hA - n, n);           // (1-z)*n + z*h
            cAr = fmaf(whAr, hA, bAr);         // pre-compute for next t
            cAz = fmaf(whAz, hA, bAz);
            gAn = fmaf(whAn, hA, bhAn);

            // ---- cell B (layer 2*lane+1), input = hA ----
            float r2 = fast_sig(fmaf(wiBr, hA, cBr));
            float z2 = fast_sig(fmaf(wiBz, hA, cBz));
            float n2 = fast_tanh(fmaf(r2, gBn, fmaf(wiBn, hA, biBn)));
            hB = fmaf(z2, hB - n2, n2);
            cBr = fmaf(whBr, hB, bBr);
            cBz = fmaf(whBz, hB, bBz);
            gBn = fmaf(whBn, hB, bhBn);

            out_val = hB;
            if (lane == 63) out[t] = hB;  // lane 63 layer B == layer 127
        }
    }
}

extern "C" void kernel_launch(void* const* d_in, const int* in_sizes, int n_in,
                              void* d_out, int out_size, void* d_ws, size_t ws_size,
                              hipStream_t stream) {
    const float* x    = (const float*)d_in[0];  // [1,256]
    const float* w_ih = (const float*)d_in[1];  // [128,3,1]
    const float* w_hh = (const float*)d_in[2];  // [128,3,1]
    const float* b_ih = (const float*)d_in[3];  // [128,3]
    const float* b_hh = (const float*)d_in[4];  // [128,3]
    float* out = (float*)d_out;                 // [1,256]

    gru_stack_wavefront<<<1, 64, 0, stream>>>(x, w_ih, w_hh, b_ih, b_hh, out);
}

// Round 2
// 106.337 us; speedup vs baseline: 1.1440x; 1.1440x over previous
//
#include <hip/hip_runtime.h>

#define T_LEN 256
#define N_LAYERS 128

// sigmoid/tanh with exp2-scale folded into the caller's coefficients:
//   sig(u)  = rcp(1 + exp2(u'))  where u' = -log2(e)   * u
//   tanh(v) = 2*rcp(1+exp2(v'))-1 where v' = -2*log2(e) * v
__device__ __forceinline__ float ex2(float x) { return __builtin_amdgcn_exp2f(x); }
__device__ __forceinline__ float rcp1p(float e) { return __builtin_amdgcn_rcpf(1.0f + e); }

// lane i <- lane i-1 within each 16-lane row (VALU pipe, ~4 cyc; lanes 0/16/32/48 keep own)
__device__ __forceinline__ float dpp_shr1(float v) {
    int i = __float_as_int(v);
    int r = __builtin_amdgcn_update_dpp(i, i, 0x111 /*row_shr:1*/, 0xF, 0xF, false);
    return __int_as_float(r);
}

// One wave, 64 lanes, 2 GRU layers per lane. Anti-diagonal wavefront with
// row-skew: lane i (row r = i>>4) computes time t = s - i - r at step s.
//  - in-row handoff (lane i-1 -> i, i%16 != 0): DPP row_shr:1, reads out_val@end(s-1). exact.
//  - cross-row handoff (lane 16r-1 -> 16r): producer finished that t at step s-2;
//    ds_bpermute issued at top of step s-1 (reading out_val@end(s-2)), consumed at s.
//    => its ~120cyc LDS latency is hidden under a full step of VALU work.
//  - lane 0 input x[s]: prefetched from LDS one step ahead (same hiding).
// State updates are cndmask-gated on t-validity, so pre/post-range steps leave
// h (and the h-derived precomputes) exactly unchanged — no garbage propagates.
__global__ __launch_bounds__(64, 1) void gru_stack_wavefront(
    const float* __restrict__ x,
    const float* __restrict__ w_ih,
    const float* __restrict__ w_hh,
    const float* __restrict__ b_ih,
    const float* __restrict__ b_hh,
    float* __restrict__ out)
{
    __shared__ float sx[T_LEN];
    const int lane = threadIdx.x;          // 0..63
    const int row  = lane >> 4;            // 0..3
    const int col  = lane & 15;
    const int skew = lane + row;           // t = s - skew; max skew 66

    #pragma unroll
    for (int i = 0; i < T_LEN / 64; ++i)
        sx[lane + 64 * i] = x[lane + 64 * i];

    const int la = 2 * lane, lb = 2 * lane + 1;
    const float L1 = -1.4426950408889634f;   // -log2(e)
    const float L2 = -2.8853900817779268f;   // -2*log2(e)

    // layer A (2*lane): scaled params
    const float wiAr = L1 * w_ih[3 * la + 0], whAr = L1 * w_hh[3 * la + 0];
    const float bAr  = L1 * (b_ih[3 * la + 0] + b_hh[3 * la + 0]);
    const float wiAz = L1 * w_ih[3 * la + 1], whAz = L1 * w_hh[3 * la + 1];
    const float bAz  = L1 * (b_ih[3 * la + 1] + b_hh[3 * la + 1]);
    const float wiAn = L2 * w_ih[3 * la + 2], biAn = L2 * b_ih[3 * la + 2];
    const float whAn = L2 * w_hh[3 * la + 2], bhAn = L2 * b_hh[3 * la + 2];
    // layer B (2*lane+1)
    const float wiBr = L1 * w_ih[3 * lb + 0], whBr = L1 * w_hh[3 * lb + 0];
    const float bBr  = L1 * (b_ih[3 * lb + 0] + b_hh[3 * lb + 0]);
    const float wiBz = L1 * w_ih[3 * lb + 1], whBz = L1 * w_hh[3 * lb + 1];
    const float bBz  = L1 * (b_ih[3 * lb + 1] + b_hh[3 * lb + 1]);
    const float wiBn = L2 * w_ih[3 * lb + 2], biBn = L2 * b_ih[3 * lb + 2];
    const float whBn = L2 * w_hh[3 * lb + 2], bhBn = L2 * b_hh[3 * lb + 2];

    float hA = 0.0f, hB = 0.0f;
    // h-dependent pre-activations (scaled): cXr = whX'·h + bX' etc. (h=0 now)
    float cAr = bAr, cAz = bAz, gAn = bhAn;
    float cBr = bBr, cBz = bBz, gBn = bhBn;

    __syncthreads();

    float out_val = 0.0f;       // this lane's layer-B output (end of prev step)
    float bnd_pending = 0.0f;   // bpermute result issued last step (out_val@end(s-2) of lane-1)
    float xcur = sx[0];         // prefetched x[s]

    const bool is_c0 = (col == 0);
    const bool is_l0 = (lane == 0);

    for (int s = 0; s < T_LEN + 66; ++s) {
        // --- communication (all reads of out_val BEFORE it is updated) ---
        float dppv     = dpp_shr1(out_val);             // end(s-1), in-row
        float bnd_next = __shfl_up(out_val, 1);         // end(s-1), consumed at s+1
        float xnext    = sx[(s + 1) & (T_LEN - 1)];     // prefetch, consumed at s+1
        float alt = is_l0 ? xcur : bnd_pending;         // both ready since last iter
        float in  = is_c0 ? alt : dppv;

        const int t = s - skew;
        const bool valid = (unsigned)t < (unsigned)T_LEN;

        // ---- cell A (layer 2*lane) ----
        float rA = rcp1p(ex2(fmaf(wiAr, in, cAr)));
        float zA = rcp1p(ex2(fmaf(wiAz, in, cAz)));
        float nA = fmaf(2.0f, rcp1p(ex2(fmaf(rA, gAn, fmaf(wiAn, in, biAn)))), -1.0f);
        float hAn = fmaf(zA, hA - nA, nA);              // (1-z)*n + z*h
        hA = valid ? hAn : hA;
        cAr = fmaf(whAr, hA, bAr);                      // off input-chain, for step s+1
        cAz = fmaf(whAz, hA, bAz);
        gAn = fmaf(whAn, hA, bhAn);

        // ---- cell B (layer 2*lane+1), input = hA ----
        float rB = rcp1p(ex2(fmaf(wiBr, hA, cBr)));
        float zB = rcp1p(ex2(fmaf(wiBz, hA, cBz)));
        float nB = fmaf(2.0f, rcp1p(ex2(fmaf(rB, gBn, fmaf(wiBn, hA, biBn)))), -1.0f);
        float hBn = fmaf(zB, hB - nB, nB);
        hB = valid ? hBn : hB;
        cBr = fmaf(whBr, hB, bBr);
        cBz = fmaf(whBz, hB, bBz);
        gBn = fmaf(whBn, hB, bhBn);

        out_val = hB;
        if (lane == 63 && valid) out[t] = hB;           // lane 63 layer B == layer 127

        xcur = xnext;
        bnd_pending = bnd_next;
    }
}

extern "C" void kernel_launch(void* const* d_in, const int* in_sizes, int n_in,
                              void* d_out, int out_size, void* d_ws, size_t ws_size,
                              hipStream_t stream) {
    const float* x    = (const float*)d_in[0];  // [1,256]
    const float* w_ih = (const float*)d_in[1];  // [128,3,1]
    const float* w_hh = (const float*)d_in[2];  // [128,3,1]
    const float* b_ih = (const float*)d_in[3];  // [128,3]
    const float* b_hh = (const float*)d_in[4];  // [128,3]
    float* out = (float*)d_out;                 // [1,256]

    gru_stack_wavefront<<<1, 64, 0, stream>>>(x, w_ih, w_hh, b_ih, b_hh, out);
}

// Round 3
// 100.492 us; speedup vs baseline: 1.2106x; 1.0582x over previous
//
#include <hip/hip_runtime.h>

#define T_LEN 256
#define N_LAYERS 128

// sigmoid/tanh with exp2-scale folded into coefficients:
//   sig(u)  = rcp(1 + exp2(u'))   where u' = -log2(e)   * u
//   tanh(v) = 2*rcp(1+exp2(v'))-1 where v' = -2*log2(e) * v
__device__ __forceinline__ float ex2(float x) { return __builtin_amdgcn_exp2f(x); }
__device__ __forceinline__ float rcp1p(float e) { return __builtin_amdgcn_rcpf(1.0f + e); }

// Full-wave lane shift: lane i <- lane i-1, all 64 lanes, VALU pipe (~1 instr).
// gfx9-lineage DPP ctrl 0x138 = wave_shr:1. Lane 0 keeps its own value
// (bound_ctrl=false, old=src) — overridden by the x-injection cndmask anyway.
__device__ __forceinline__ float dpp_wave_shr1(float v) {
    int i = __float_as_int(v);
    int r = __builtin_amdgcn_update_dpp(i, i, 0x138, 0xF, 0xF, false);
    return __int_as_float(r);
}

// One wave, 64 lanes, 2 GRU layers per lane (layers 2*lane, 2*lane+1).
// Anti-diagonal wavefront: at step s, lane i computes time t = s - i.
// Handoff lane i-1 -> i is a single DPP wave_shr:1 (no LDS, no skew).
// Lane 0's input x[s] is prefetched from LDS one step ahead (off-chain).
// h-updates are cndmask-gated on t-validity so ramp-in/out steps leave state
// exactly unchanged.
__global__ __launch_bounds__(64, 1) void gru_stack_wavefront(
    const float* __restrict__ x,
    const float* __restrict__ w_ih,
    const float* __restrict__ w_hh,
    const float* __restrict__ b_ih,
    const float* __restrict__ b_hh,
    float* __restrict__ out)
{
    __shared__ float sx[T_LEN];
    const int lane = threadIdx.x;  // 0..63

    #pragma unroll
    for (int i = 0; i < T_LEN / 64; ++i)
        sx[lane + 64 * i] = x[lane + 64 * i];

    const int la = 2 * lane, lb = 2 * lane + 1;
    const float L1 = -1.4426950408889634f;   // -log2(e)
    const float L2 = -2.8853900817779268f;   // -2*log2(e)

    // layer A (2*lane): exp2-scaled params
    const float wiAr = L1 * w_ih[3 * la + 0], whAr = L1 * w_hh[3 * la + 0];
    const float bAr  = L1 * (b_ih[3 * la + 0] + b_hh[3 * la + 0]);
    const float wiAz = L1 * w_ih[3 * la + 1], whAz = L1 * w_hh[3 * la + 1];
    const float bAz  = L1 * (b_ih[3 * la + 1] + b_hh[3 * la + 1]);
    const float wiAn = L2 * w_ih[3 * la + 2], biAn = L2 * b_ih[3 * la + 2];
    const float whAn = L2 * w_hh[3 * la + 2], bhAn = L2 * b_hh[3 * la + 2];
    // layer B (2*lane+1)
    const float wiBr = L1 * w_ih[3 * lb + 0], whBr = L1 * w_hh[3 * lb + 0];
    const float bBr  = L1 * (b_ih[3 * lb + 0] + b_hh[3 * lb + 0]);
    const float wiBz = L1 * w_ih[3 * lb + 1], whBz = L1 * w_hh[3 * lb + 1];
    const float bBz  = L1 * (b_ih[3 * lb + 1] + b_hh[3 * lb + 1]);
    const float wiBn = L2 * w_ih[3 * lb + 2], biBn = L2 * b_ih[3 * lb + 2];
    const float whBn = L2 * w_hh[3 * lb + 2], bhBn = L2 * b_hh[3 * lb + 2];

    float hA = 0.0f, hB = 0.0f;
    // h-dependent pre-activations (scaled), computed off the input chain.
    float cAr = bAr, cAz = bAz, gAn = bhAn;
    float cBr = bBr, cBz = bBz, gBn = bhBn;

    __syncthreads();

    float out_val = 0.0f;       // this lane's layer-B output at end of prev step
    float xcur = sx[0];         // prefetched x[s]
    const bool is_l0 = (lane == 0);
    const bool is_l63 = (lane == 63);

    #pragma unroll 4
    for (int s = 0; s < T_LEN + 63; ++s) {
        // --- handoff: single VALU-pipe wave shift; lane 0 injects x[s] ---
        float shifted = dpp_wave_shr1(out_val);
        float in = is_l0 ? xcur : shifted;
        float xnext = sx[(s + 1) & (T_LEN - 1)];   // off-chain prefetch for s+1

        const int t = s - lane;
        const bool valid = (unsigned)t < (unsigned)T_LEN;

        // ---- cell A (layer 2*lane), input = in ----
        float rA = rcp1p(ex2(fmaf(wiAr, in, cAr)));
        float zA = rcp1p(ex2(fmaf(wiAz, in, cAz)));
        float nA = fmaf(2.0f, rcp1p(ex2(fmaf(rA, gAn, fmaf(wiAn, in, biAn)))), -1.0f);
        float hAn = fmaf(zA, hA - nA, nA);          // (1-z)*n + z*h
        hA = valid ? hAn : hA;
        cAr = fmaf(whAr, hA, bAr);                  // for step s+1, off input chain
        cAz = fmaf(whAz, hA, bAz);
        gAn = fmaf(whAn, hA, bhAn);

        // ---- cell B (layer 2*lane+1), input = hA ----
        float rB = rcp1p(ex2(fmaf(wiBr, hA, cBr)));
        float zB = rcp1p(ex2(fmaf(wiBz, hA, cBz)));
        float nB = fmaf(2.0f, rcp1p(ex2(fmaf(rB, gBn, fmaf(wiBn, hA, biBn)))), -1.0f);
        float hBn = fmaf(zB, hB - nB, nB);
        hB = valid ? hBn : hB;
        cBr = fmaf(whBr, hB, bBr);
        cBz = fmaf(whBz, hB, bBz);
        gBn = fmaf(whBn, hB, bhBn);

        out_val = hB;
        if (is_l63 && valid) out[t] = hB;           // lane 63 layer B == layer 127

        xcur = xnext;
    }
}

extern "C" void kernel_launch(void* const* d_in, const int* in_sizes, int n_in,
                              void* d_out, int out_size, void* d_ws, size_t ws_size,
                              hipStream_t stream) {
    const float* x    = (const float*)d_in[0];  // [1,256]
    const float* w_ih = (const float*)d_in[1];  // [128,3,1]
    const float* w_hh = (const float*)d_in[2];  // [128,3,1]
    const float* b_ih = (const float*)d_in[3];  // [128,3]
    const float* b_hh = (const float*)d_in[4];  // [128,3]
    float* out = (float*)d_out;                 // [1,256]

    gru_stack_wavefront<<<1, 64, 0, stream>>>(x, w_ih, w_hh, b_ih, b_hh, out);
}